// Round 4
// baseline (7492.907 us; speedup 1.0000x reference)
//
#include <hip/hip_runtime.h>
#include <math.h>

#define A_NUM 9
#define NCLS 80
#define IMG_KEY 3916800   // 720*5440
#define IMG_REG 195840    // 36*5440
#define CAP 8192
#define HBINS 16384
#define CONCAT_PX 5440

__constant__ int   c_W[4]       = {64, 32, 16, 8};
__constant__ int   c_stride[4]  = {8, 16, 32, 64};
__constant__ float c_sizes[4][3]= {{32.f,40.f,50.f},{64.f,80.f,101.f},{128.f,161.f,203.f},{256.f,322.f,406.f}};
__constant__ int   c_keyOff[4]  = {0, 2949120, 3686400, 3870720};
__constant__ int   c_keyCnt[4]  = {2949120, 737280, 184320, 46080};
__constant__ int   c_regOff[4]  = {0, 147456, 184320, 193536};
__constant__ int   c_lvlPx[4]   = {0, 4096, 5120, 5376};

// ---------------------------------------------------------------------------
// Fused 3x3 SAME conv, fp32. 16x16-px tile x 64 co per block; thread tile
// 4co x (4x4)px -> 4608 FMA per 8-ci chunk (vs ~2040 DS cyc): FMA-bound.
// mode 0: tower layer, 1-D grid, (head,coGroup)=blockIdx%8 -> XCD-pinned
//         weights (576 KB slab stays L2-resident per XCD).
// mode 1: out-convs (3-D grid; y<12 cls->keys, y==12 reg->regb).
// Register-prefetch: next chunk's global loads issued right after barrier.
// ---------------------------------------------------------------------------
__global__ __launch_bounds__(256, 3) void conv_fused(
    const float* __restrict__ f0, const float* __restrict__ f1,
    const float* __restrict__ f2, const float* __restrict__ f3,
    const float* __restrict__ bufIn, float* __restrict__ bufOut,
    const float* __restrict__ wA, const float* __restrict__ bA,
    const float* __restrict__ wB, const float* __restrict__ bB,
    unsigned* __restrict__ keys, float* __restrict__ regb,
    int layer, int mode)
{
    const int tid = threadIdx.x;
    int t22, img, head, coBase, C_out, epi;
    if (mode == 0) {
        int b = blockIdx.x;
        int combo = b & 7, rest = b >> 3;
        img = rest & 3; t22 = rest >> 2;
        head = combo >> 2; coBase = (combo & 3) * 64; C_out = 256; epi = 0;
    } else {
        t22 = blockIdx.x; img = blockIdx.z;
        if (blockIdx.y < 12) { head = 0; coBase = blockIdx.y * 64; C_out = 720; epi = 1; }
        else                 { head = 1; coBase = 0;               C_out = 36;  epi = 2; }
    }
    const float* wsel = head ? wB : wA;
    const float* bsel = head ? bB : bA;

    int lvl, ty, tx;
    if (t22 < 16)      { lvl = 0; ty = t22 >> 2; tx = t22 & 3; }
    else if (t22 < 20) { int u = t22 - 16; lvl = 1; ty = u >> 1; tx = u & 1; }
    else if (t22 == 20){ lvl = 2; ty = 0; tx = 0; }
    else               { lvl = 3; ty = 0; tx = 0; }
    const int W = 64 >> lvl, H = W, HW = W * W;
    const int tileY = ty * 16, tileX = tx * 16;

    const float* srcBase; int chStride;
    if (mode == 0 && layer == 0) {
        const float* f = (lvl == 0) ? f0 : ((lvl == 1) ? f1 : ((lvl == 2) ? f2 : f3));
        srcBase = f + (size_t)img * 256 * HW; chStride = HW;
    } else {
        srcBase = bufIn + ((size_t)(head * 4 + img) * 256) * CONCAT_PX + c_lvlPx[lvl];
        chStride = CONCAT_PX;
    }
    const float* wBase = wsel + (size_t)coBase * 2304;

    const int cog4 = (tid >> 4) * 4;
    const int pg   = tid & 15;
    const int py0  = (pg >> 2) * 4;
    const int px0  = (pg & 3) * 4;

    __shared__ float sIn[2880];   // 8ci x 18 rows x 20 cols (18 valid + pad)
    __shared__ float sW[6400];    // [coL*100 + ci*12 + k]

    // precomputed staging tables
    int inOff[12];
    #pragma unroll
    for (int e = 0; e < 12; ++e) {
        int t = tid + e * 256;
        int off = -1;
        if (t < 2880) {
            int ci = t / 360, rem = t - ci * 360;
            int iy = rem / 20, ix = rem - iy * 20;
            int gy = tileY + iy - 1, gx = tileX + ix - 1;
            if (ix < 18 && (unsigned)gy < (unsigned)H && (unsigned)gx < (unsigned)W)
                off = ci * chStride + gy * W + gx;
        }
        inOff[e] = off;
    }
    unsigned wPack[18];   // (gOff<<13) | ldsOff ; bit31 = invalid(co>=C_out)
    #pragma unroll
    for (int e = 0; e < 18; ++e) {
        int t = tid + e * 256;                 // t < 4608
        int coL = t / 72, rem = t - coL * 72;
        int ciL = rem / 9, kk = rem - ciL * 9;
        unsigned lds = (unsigned)(coL * 100 + ciL * 12 + kk);
        unsigned g   = (unsigned)(coL * 2304 + ciL * 9 + kk);
        wPack[e] = (coBase + coL < C_out) ? ((g << 13) | lds) : (0x80000000u | lds);
    }

    float rIn[12], rW[18];
    auto loadIn = [&](int cc) {
        const float* isrc = srcBase + cc * chStride;
        #pragma unroll
        for (int e = 0; e < 12; ++e)
            rIn[e] = (inOff[e] >= 0) ? isrc[inOff[e]] : 0.f;
    };
    auto loadW = [&](int cc) {
        const float* wsrc = wBase + cc * 9;
        #pragma unroll
        for (int e = 0; e < 18; ++e) {
            unsigned p = wPack[e];
            rW[e] = (p & 0x80000000u) ? 0.f : wsrc[p >> 13];
        }
    };

    float acc[4][16] = {};
    loadIn(0); loadW(0);

    for (int cc = 0; cc < 256; cc += 8) {
        #pragma unroll
        for (int e = 0; e < 12; ++e) {
            int t = tid + e * 256;
            if (t < 2880) sIn[t] = rIn[e];
        }
        #pragma unroll
        for (int e = 0; e < 18; ++e)
            sW[wPack[e] & 8191u] = rW[e];
        __syncthreads();
        if (cc + 8 < 256) { loadIn(cc + 8); loadW(cc + 8); }

        #pragma unroll
        for (int ci = 0; ci < 8; ++ci) {
            float xr[6][6];
            #pragma unroll
            for (int iy = 0; iy < 6; ++iy) {
                const float4 a = *reinterpret_cast<const float4*>(&sIn[ci * 360 + (py0 + iy) * 20 + px0]);
                const float2 b = *reinterpret_cast<const float2*>(&sIn[ci * 360 + (py0 + iy) * 20 + px0 + 4]);
                xr[iy][0] = a.x; xr[iy][1] = a.y; xr[iy][2] = a.z; xr[iy][3] = a.w;
                xr[iy][4] = b.x; xr[iy][5] = b.y;
            }
            #pragma unroll
            for (int r = 0; r < 4; ++r) {
                const int wb = (cog4 + r) * 100 + ci * 12;
                const float4 w0 = *reinterpret_cast<const float4*>(&sW[wb]);
                const float4 w1 = *reinterpret_cast<const float4*>(&sW[wb + 4]);
                const float  w8 = sW[wb + 8];
                float wr[9];
                wr[0] = w0.x; wr[1] = w0.y; wr[2] = w0.z; wr[3] = w0.w;
                wr[4] = w1.x; wr[5] = w1.y; wr[6] = w1.z; wr[7] = w1.w; wr[8] = w8;
                #pragma unroll
                for (int oy = 0; oy < 4; ++oy)
                    #pragma unroll
                    for (int ox = 0; ox < 4; ++ox) {
                        float s = acc[r][oy * 4 + ox];
                        #pragma unroll
                        for (int ky = 0; ky < 3; ++ky)
                            #pragma unroll
                            for (int kx = 0; kx < 3; ++kx)
                                s = fmaf(xr[oy + ky][ox + kx], wr[ky * 3 + kx], s);
                        acc[r][oy * 4 + ox] = s;
                    }
            }
        }
        __syncthreads();
    }

    if (px0 >= W) return;   // lvl3 right-half threads
    #pragma unroll
    for (int r = 0; r < 4; ++r) {
        int coG = coBase + cog4 + r;
        if (coG >= C_out) continue;
        float b = bsel[coG];
        for (int oy = 0; oy < 4; ++oy) {
            int y = tileY + py0 + oy;
            if (y >= H) continue;   // lvl3 bottom rows
            float v0 = acc[r][oy * 4 + 0] + b;
            float v1 = acc[r][oy * 4 + 1] + b;
            float v2 = acc[r][oy * 4 + 2] + b;
            float v3 = acc[r][oy * 4 + 3] + b;
            if (epi == 0) {
                v0 = fmaxf(v0, 0.f); v1 = fmaxf(v1, 0.f); v2 = fmaxf(v2, 0.f); v3 = fmaxf(v3, 0.f);
                float* o = bufOut + ((size_t)(head * 4 + img) * 256 + coG) * CONCAT_PX
                                  + c_lvlPx[lvl] + y * W + tileX + px0;
                *reinterpret_cast<float4*>(o) = make_float4(v0, v1, v2, v3);
            } else if (epi == 1) {
                float s0 = 1.0f / (1.0f + expf(-v0));
                float s1 = 1.0f / (1.0f + expf(-v1));
                float s2 = 1.0f / (1.0f + expf(-v2));
                float s3 = 1.0f / (1.0f + expf(-v3));
                unsigned k0 = (s0 > 0.05f) ? __float_as_uint(s0) : 0u;
                unsigned k1 = (s1 > 0.05f) ? __float_as_uint(s1) : 0u;
                unsigned k2 = (s2 > 0.05f) ? __float_as_uint(s2) : 0u;
                unsigned k3 = (s3 > 0.05f) ? __float_as_uint(s3) : 0u;
                unsigned* o = keys + (size_t)img * IMG_KEY + c_keyOff[lvl]
                                   + (size_t)coG * HW + y * W + tileX + px0;
                *reinterpret_cast<uint4*>(o) = make_uint4(k0, k1, k2, k3);
            } else {
                int a = coG >> 2, jj = coG & 3;
                int pBase = y * W + tileX + px0;
                #pragma unroll
                for (int px = 0; px < 4; ++px) {
                    float v = acc[r][oy * 4 + px] + b;
                    regb[(size_t)img * IMG_REG + c_regOff[lvl] + (size_t)((pBase + px) * A_NUM + a) * 4 + jj] = v;
                }
            }
        }
    }
}

// ---------------------------------------------------------------------------
__global__ __launch_bounds__(256) void hist_k(const unsigned* __restrict__ keys,
                                              unsigned* __restrict__ hist)
{
    int il = blockIdx.y, img = il >> 2, lvl = il & 3;
    int n = c_keyCnt[lvl];
    int chunk = blockIdx.x * 16384;
    if (chunk >= n) return;
    __shared__ unsigned h[HBINS];   // 64 KB
    for (int t = threadIdx.x; t < HBINS; t += 256) h[t] = 0;
    __syncthreads();
    const uint4* k4 = (const uint4*)(keys + (size_t)img * IMG_KEY + c_keyOff[lvl]);
    int i0 = chunk >> 2, i1 = min(chunk + 16384, n) >> 2;
    for (int i = i0 + (int)threadIdx.x; i < i1; i += 256) {
        uint4 kv = k4[i];
        if (kv.x) atomicAdd(&h[kv.x >> 18], 1u);
        if (kv.y) atomicAdd(&h[kv.y >> 18], 1u);
        if (kv.z) atomicAdd(&h[kv.z >> 18], 1u);
        if (kv.w) atomicAdd(&h[kv.w >> 18], 1u);
    }
    __syncthreads();
    unsigned* gh = hist + (size_t)il * HBINS;
    for (int t = threadIdx.x; t < HBINS; t += 256)
        if (h[t]) atomicAdd(&gh[t], h[t]);
}

__global__ __launch_bounds__(256) void thresh_k(const unsigned* __restrict__ hist,
                                                unsigned* __restrict__ tbin)
{
    const unsigned* h = hist + (size_t)blockIdx.x * HBINS;
    __shared__ unsigned cs[256];
    int tid = threadIdx.x;
    unsigned s = 0;
    int base = tid * 64;
    for (int q = 0; q < 64; ++q) { int b = base + q; if (b >= 1) s += h[b]; }
    cs[tid] = s;
    __syncthreads();
    if (tid == 0) {
        unsigned total = 0, sel = 0;
        for (int c = 255; c >= 0; --c) {
            if (total + cs[c] >= 100u) {
                int lo = (c == 0) ? 1 : c * 64;
                for (int b = c * 64 + 63; b >= lo; --b) {
                    total += h[b];
                    if (total >= 100u) { sel = (unsigned)b; break; }
                }
                break;
            }
            total += cs[c];
        }
        tbin[blockIdx.x] = sel;
    }
}

// two-pass per-block aggregation: ONE global atomic per block
__global__ __launch_bounds__(256) void compact_k(const unsigned* __restrict__ keys,
                                                 const unsigned* __restrict__ tbin,
                                                 unsigned* __restrict__ cnt,
                                                 uint2* __restrict__ comp)
{
    int il = blockIdx.y, img = il >> 2, lvl = il & 3;
    int n = c_keyCnt[lvl];
    int chunk = blockIdx.x * 16384;
    if (chunk >= n) return;
    const unsigned* kbase = keys + (size_t)img * IMG_KEY + c_keyOff[lvl];
    const uint4* k4 = (const uint4*)kbase;
    unsigned thr = tbin[il] << 18;
    int shift = 12 - 2 * lvl;
    int hwm = (1 << shift) - 1;
    int i0 = chunk >> 2, i1 = min(chunk + 16384, n) >> 2;
    __shared__ unsigned lcnt, lbase, lcur;
    if (threadIdx.x == 0) { lcnt = 0; lcur = 0; }
    __syncthreads();
    unsigned myc = 0;
    for (int i = i0 + (int)threadIdx.x; i < i1; i += 256) {
        uint4 kv = k4[i];
        myc += (kv.x != 0u && kv.x >= thr);
        myc += (kv.y != 0u && kv.y >= thr);
        myc += (kv.z != 0u && kv.z >= thr);
        myc += (kv.w != 0u && kv.w >= thr);
    }
    if (myc) atomicAdd(&lcnt, myc);
    __syncthreads();
    if (threadIdx.x == 0 && lcnt) lbase = atomicAdd(&cnt[il], lcnt);
    __syncthreads();
    if (lcnt == 0) return;
    uint2* c = comp + (size_t)il * CAP;
    for (int i = i0 + (int)threadIdx.x; i < i1; i += 256) {
        uint4 kv = k4[i];
        unsigned kk[4] = {kv.x, kv.y, kv.z, kv.w};
        #pragma unroll
        for (int j = 0; j < 4; ++j) {
            unsigned key = kk[j];
            if (key != 0u && key >= thr) {
                int t = i * 4 + j;
                int co = t >> shift, p = t & hwm;
                int a = co / NCLS, cls = co - a * NCLS;
                unsigned idx = (unsigned)((p * A_NUM + a) * NCLS + cls);
                unsigned pos = lbase + atomicAdd(&lcur, 1u);
                if (pos < CAP) c[pos] = make_uint2(key, idx);
            }
        }
    }
}

// single-block bitonic sort of up to CAP candidates -> exact top-100
__global__ __launch_bounds__(256) void topsort_k(const unsigned* __restrict__ cnt,
                                                 const uint2* __restrict__ comp,
                                                 uint2* __restrict__ topk)
{
    __shared__ unsigned long long s[CAP];   // 64 KB
    int il = blockIdx.x, tid = threadIdx.x;
    int n = (int)min(cnt[il], (unsigned)CAP);
    const uint2* c = comp + (size_t)il * CAP;
    for (int i = tid; i < CAP; i += 256) {
        unsigned long long v = 0ull;
        if (i < n) {
            uint2 e = c[i];
            v = ((unsigned long long)e.x << 32) | (unsigned long long)(~e.y);
        }
        s[i] = v;
    }
    for (int k = 2; k <= CAP; k <<= 1) {
        for (int j = k >> 1; j > 0; j >>= 1) {
            __syncthreads();
            for (int p = tid; p < CAP / 2; p += 256) {
                int i = ((p & ~(j - 1)) << 1) | (p & (j - 1));
                int ixj = i | j;
                unsigned long long a = s[i], b = s[ixj];
                if (((i & k) == 0) ? (a < b) : (a > b)) { s[i] = b; s[ixj] = a; }
            }
        }
    }
    __syncthreads();
    if (tid < 100) {
        unsigned long long v = s[tid];
        topk[il * 100 + tid] = make_uint2((unsigned)(v >> 32), ~(unsigned)(v & 0xFFFFFFFFull));
    }
}

// ---------------------------------------------------------------------------
__global__ void decode_k(const uint2* __restrict__ topk, const float* __restrict__ regb,
                         float* __restrict__ cboxes, float* __restrict__ cscores,
                         int* __restrict__ clabels, const int* __restrict__ ph, const int* __restrict__ pw)
{
    int il = blockIdx.x, img = il >> 2, lvl = il & 3;
    int j = threadIdx.x;
    if (j >= 100) return;
    float imgW = (float)pw[0], imgH = (float)ph[0];
    uint2 tk = topk[il * 100 + j];
    int outP = img * 400 + lvl * 100 + j;
    if (tk.x == 0u) {
        cboxes[outP * 4 + 0] = 0.f; cboxes[outP * 4 + 1] = 0.f;
        cboxes[outP * 4 + 2] = 0.f; cboxes[outP * 4 + 3] = 0.f;
        cscores[outP] = -1.0f; clabels[outP] = -1;
        return;
    }
    float score = __uint_as_float(tk.x);
    unsigned idx = tk.y;
    int aidx = (int)(idx / NCLS);
    int lbl  = (int)(idx - (unsigned)aidx * NCLS);
    int a = aidx % A_NUM, p = aidx / A_NUM;
    int W = c_W[lvl];
    int y = p / W, x = p - y * W;
    int r = a / 3, si = a - r * 3;
    float ratio = (r == 0) ? 0.5f : ((r == 1) ? 1.0f : 2.0f);
    float size = c_sizes[lvl][si];
    float hr = sqrtf(ratio);
    float wr = 1.0f / hr;
    float wsz = wr * size, hsz = hr * size;
    float bw = rintf(wsz * 0.5f), bh = rintf(hsz * 0.5f);
    float sx = (float)(x * c_stride[lvl]), sy = (float)(y * c_stride[lvl]);
    float ax1 = fminf(fmaxf(sx - bw, 0.f), imgW);
    float ay1 = fminf(fmaxf(sy - bh, 0.f), imgH);
    float ax2 = fminf(fmaxf(sx + bw, 0.f), imgW);
    float ay2 = fminf(fmaxf(sy + bh, 0.f), imgH);
    float aw = ax2 - ax1, ah = ay2 - ay1;
    float cx = ax1 + 0.5f * aw, cy = ay1 + 0.5f * ah;
    const float* rel = regb + (size_t)img * IMG_REG + c_regOff[lvl] + (size_t)aidx * 4;
    float dx = rel[0], dy = rel[1];
    float dw = fminf(rel[2], 4.135166556742356f);
    float dh = fminf(rel[3], 4.135166556742356f);
    float pcx = dx * aw + cx, pcy = dy * ah + cy;
    float pwd = expf(dw) * aw, phd = expf(dh) * ah;
    float x1 = pcx - 0.5f * pwd, y1 = pcy - 0.5f * phd;
    float x2 = pcx + 0.5f * pwd, y2 = pcy + 0.5f * phd;
    cboxes[outP * 4 + 0] = fminf(fmaxf(x1, 0.f), imgW);
    cboxes[outP * 4 + 1] = fminf(fmaxf(y1, 0.f), imgH);
    cboxes[outP * 4 + 2] = fminf(fmaxf(x2, 0.f), imgW);
    cboxes[outP * 4 + 3] = fminf(fmaxf(y2, 0.f), imgH);
    cscores[outP] = score;
    clabels[outP] = lbl;
}

__global__ __launch_bounds__(512) void nms_k(const float* __restrict__ cboxes,
                                             const float* __restrict__ cscores,
                                             const int* __restrict__ clabels,
                                             const int* __restrict__ ph, const int* __restrict__ pw,
                                             float* __restrict__ out)
{
    int img = blockIdx.x, tid = threadIdx.x;
    __shared__ float sSc[512];
    __shared__ int   sPos[512];
    __shared__ float bx1[400], by1[400], bx2[400], by2[400], sAr[400];
    __shared__ int   sKeep[400], sLbl[400];
    float imgH = (float)ph[0], imgW = (float)pw[0];
    float offm = fmaxf(imgH, imgW) + 1.0f;

    sSc[tid] = (tid < 400) ? cscores[img * 400 + tid] : -3.0f;
    sPos[tid] = tid;
    __syncthreads();

    for (int k = 2; k <= 512; k <<= 1) {
        for (int jj = k >> 1; jj > 0; jj >>= 1) {
            int ixj = tid ^ jj;
            if (ixj > tid) {
                float s1 = sSc[tid], s2 = sSc[ixj];
                int p1 = sPos[tid], p2 = sPos[ixj];
                bool bef = (s1 > s2) || (s1 == s2 && p1 < p2);
                bool sw = ((tid & k) == 0) ? (!bef) : bef;
                if (sw) { sSc[tid] = s2; sSc[ixj] = s1; sPos[tid] = p2; sPos[ixj] = p1; }
            }
            __syncthreads();
        }
    }

    if (tid < 400) {
        int p = sPos[tid];
        int lbl = clabels[img * 400 + p];
        float ofs = (float)lbl * offm;
        float x1 = cboxes[(img * 400 + p) * 4 + 0] + ofs;
        float y1 = cboxes[(img * 400 + p) * 4 + 1] + ofs;
        float x2 = cboxes[(img * 400 + p) * 4 + 2] + ofs;
        float y2 = cboxes[(img * 400 + p) * 4 + 3] + ofs;
        bx1[tid] = x1; by1[tid] = y1; bx2[tid] = x2; by2[tid] = y2;
        sAr[tid] = (x2 - x1) * (y2 - y1);
        sLbl[tid] = lbl;
        sKeep[tid] = (sSc[tid] > 0.05f) ? 1 : 0;
    }
    __syncthreads();

    for (int i = 0; i < 400; ++i) {
        if (sKeep[i]) {
            for (int j2 = i + 1 + tid; j2 < 400; j2 += 512) {
                float ltx = fmaxf(bx1[i], bx1[j2]), lty = fmaxf(by1[i], by1[j2]);
                float rbx = fminf(bx2[i], bx2[j2]), rby = fminf(by2[i], by2[j2]);
                float ww = fmaxf(rbx - ltx, 0.f), hh = fmaxf(rby - lty, 0.f);
                float inter = ww * hh;
                float iou = inter / (((sAr[i] + sAr[j2]) - inter) + 1e-9f);
                if (iou > 0.5f) sKeep[j2] = 0;
            }
        }
        __syncthreads();
    }

    if (tid == 0) {
        int rank = 0;
        for (int i = 0; i < 400 && rank < 100; ++i) {
            if (sKeep[i]) {
                int p = sPos[i];
                for (int kk = 0; kk < 4; ++kk)
                    out[(img * 100 + rank) * 4 + kk] = cboxes[(img * 400 + p) * 4 + kk];
                out[1600 + img * 100 + rank] = sSc[i];
                out[2000 + img * 100 + rank] = (float)sLbl[i];
                ++rank;
            }
        }
        for (; rank < 100; ++rank) {
            for (int kk = 0; kk < 4; ++kk) out[(img * 100 + rank) * 4 + kk] = 0.f;
            out[1600 + img * 100 + rank] = 0.f;
            out[2000 + img * 100 + rank] = -1.0f;
        }
    }
}

// ---------------------------------------------------------------------------
extern "C" void kernel_launch(void* const* d_in, const int* in_sizes, int n_in,
                              void* d_out, int out_size, void* d_ws, size_t ws_size,
                              hipStream_t stream)
{
    const float* f0 = (const float*)d_in[0];
    const float* f1 = (const float*)d_in[1];
    const float* f2 = (const float*)d_in[2];
    const float* f3 = (const float*)d_in[3];
    const float* cls_tw = (const float*)d_in[4];
    const float* cls_tb = (const float*)d_in[5];
    const float* cls_ow = (const float*)d_in[6];
    const float* cls_ob = (const float*)d_in[7];
    const float* reg_tw = (const float*)d_in[8];
    const float* reg_tb = (const float*)d_in[9];
    const float* reg_ow = (const float*)d_in[10];
    const float* reg_ob = (const float*)d_in[11];
    const int* ph = (const int*)d_in[12];
    const int* pw = (const int*)d_in[13];
    float* out = (float*)d_out;

    char* ws = (char*)d_ws;
    size_t off = 0;
    auto alloc = [&](size_t bytes) -> void* {
        void* p = ws + off;
        off = (off + bytes + 255) & ~(size_t)255;
        return p;
    };
    // bufA aliased with keys (tower ping slab fits inside keys; keys written
    // only by the out-conv, after bufA's last read).
    float*    bufA   = (float*)alloc((size_t)4 * IMG_KEY * 4);                 // 62.7 MB
    unsigned* keys   = (unsigned*)bufA;
    float*    bufB   = (float*)alloc((size_t)2 * 4 * 256 * CONCAT_PX * 4);     // 44.6 MB
    float*    regb   = (float*)alloc((size_t)4 * IMG_REG * 4);
    unsigned* hist   = (unsigned*)alloc((size_t)16 * HBINS * 4);               // 1 MB
    unsigned* cnt    = (unsigned*)alloc(16 * 4);
    unsigned* tbin   = (unsigned*)alloc(16 * 4);
    uint2*    comp   = (uint2*)alloc((size_t)16 * CAP * 8);                    // 1 MB
    uint2*    topk   = (uint2*)alloc((size_t)1600 * 8);
    float*    cboxes = (float*)alloc((size_t)4 * 400 * 4 * 4);
    float*    cscores= (float*)alloc((size_t)4 * 400 * 4);
    int*      clabels= (int*)alloc((size_t)4 * 400 * 4);

    hipMemsetAsync(hist, 0, (size_t)16 * HBINS * 4, stream);
    hipMemsetAsync(cnt, 0, 64, stream);

    const size_t LW = (size_t)256 * 256 * 9;
    // tower: L0 f->A, L1 A->B, L2 B->A, L3 A->B
    float* seqIn[4]  = {nullptr, bufA, bufB, bufA};
    float* seqOut[4] = {bufA, bufB, bufA, bufB};
    for (int layer = 0; layer < 4; ++layer) {
        conv_fused<<<dim3(704), 256, 0, stream>>>(
            f0, f1, f2, f3, seqIn[layer], seqOut[layer],
            cls_tw + LW * layer, cls_tb + 256 * layer,
            reg_tw + LW * layer, reg_tb + 256 * layer,
            nullptr, nullptr, layer, 0);
    }
    // fused out-convs: reads bufB, writes keys(=bufA) + regb
    conv_fused<<<dim3(22, 13, 4), 256, 0, stream>>>(
        f0, f1, f2, f3, bufB, nullptr,
        cls_ow, cls_ob, reg_ow, reg_ob,
        keys, regb, 4, 1);

    hist_k<<<dim3(180, 16), 256, 0, stream>>>(keys, hist);
    thresh_k<<<16, 256, 0, stream>>>(hist, tbin);
    compact_k<<<dim3(180, 16), 256, 0, stream>>>(keys, tbin, cnt, comp);
    topsort_k<<<16, 256, 0, stream>>>(cnt, comp, topk);
    decode_k<<<16, 128, 0, stream>>>(topk, regb, cboxes, cscores, clabels, ph, pw);
    nms_k<<<4, 512, 0, stream>>>(cboxes, cscores, clabels, ph, pw, out);
}

// Round 5
// 6011.532 us; speedup vs baseline: 1.2464x; 1.2464x over previous
//
#include <hip/hip_runtime.h>
#include <math.h>

#define A_NUM 9
#define NCLS 80
#define IMG_KEY 3916800   // 720*5440
#define IMG_REG 195840    // 36*5440
#define CAP 8192
#define HBINS 16384
#define CONCAT_PX 5440

__constant__ int   c_W[4]       = {64, 32, 16, 8};
__constant__ int   c_stride[4]  = {8, 16, 32, 64};
__constant__ float c_sizes[4][3]= {{32.f,40.f,50.f},{64.f,80.f,101.f},{128.f,161.f,203.f},{256.f,322.f,406.f}};
__constant__ int   c_keyOff[4]  = {0, 2949120, 3686400, 3870720};
__constant__ int   c_keyCnt[4]  = {2949120, 737280, 184320, 46080};
__constant__ int   c_regOff[4]  = {0, 147456, 184320, 193536};
__constant__ int   c_lvlPx[4]   = {0, 4096, 5120, 5376};

// ---------------------------------------------------------------------------
// Fused 3x3 SAME conv, fp32. 16x16-px tile x 64 co per block; thread tile
// 4co x (4x4)px -> 4608 FMA per 8-ci chunk vs ~2040 DS cyc: FMA-bound.
// __launch_bounds__(256,2): VGPR cap 256 so the 64-acc + 36-fragment +
// 30-prefetch register set fits WITHOUT scratch spill (R4's 84-VGPR cap
// spilled -> 3.2 GB/dispatch scratch writes, the R4 regression).
// mode 0: tower layer, grid (22 tiles, 4 coGroups, head*4+img).
// mode 1: out-convs (y<12 cls->keys, y==12 reg->regb).
// ---------------------------------------------------------------------------
__global__ __launch_bounds__(256, 2) void conv_fused(
    const float* __restrict__ f0, const float* __restrict__ f1,
    const float* __restrict__ f2, const float* __restrict__ f3,
    const float* __restrict__ bufIn, float* __restrict__ bufOut,
    const float* __restrict__ wA, const float* __restrict__ bA,
    const float* __restrict__ wB, const float* __restrict__ bB,
    unsigned* __restrict__ keys, float* __restrict__ regb,
    int layer, int mode)
{
    const int tid = threadIdx.x;
    int t22 = blockIdx.x;
    int img, head, coBase, C_out, epi;
    if (mode == 0) {
        img = blockIdx.z & 3; head = blockIdx.z >> 2;
        coBase = blockIdx.y * 64; C_out = 256; epi = 0;
    } else {
        img = blockIdx.z;
        if (blockIdx.y < 12) { head = 0; coBase = blockIdx.y * 64; C_out = 720; epi = 1; }
        else                 { head = 1; coBase = 0;               C_out = 36;  epi = 2; }
    }
    const float* wsel = head ? wB : wA;
    const float* bsel = head ? bB : bA;

    int lvl, ty, tx;
    if (t22 < 16)      { lvl = 0; ty = t22 >> 2; tx = t22 & 3; }
    else if (t22 < 20) { int u = t22 - 16; lvl = 1; ty = u >> 1; tx = u & 1; }
    else if (t22 == 20){ lvl = 2; ty = 0; tx = 0; }
    else               { lvl = 3; ty = 0; tx = 0; }
    const int W = 64 >> lvl, H = W, HW = W * W;
    const int tileY = ty * 16, tileX = tx * 16;

    const float* srcBase; int chStride;
    if (mode == 0 && layer == 0) {
        const float* f = (lvl == 0) ? f0 : ((lvl == 1) ? f1 : ((lvl == 2) ? f2 : f3));
        srcBase = f + (size_t)img * 256 * HW; chStride = HW;
    } else {
        srcBase = bufIn + ((size_t)(head * 4 + img) * 256) * CONCAT_PX + c_lvlPx[lvl];
        chStride = CONCAT_PX;
    }
    const float* wBase = wsel + (size_t)coBase * 2304;

    const int cog4 = (tid >> 4) * 4;
    const int pg   = tid & 15;
    const int py0  = (pg >> 2) * 4;
    const int px0  = (pg & 3) * 4;

    __shared__ float sIn[2880];   // 8ci x 18 rows x 20 cols (18 valid + pad)
    __shared__ float sW[6400];    // [coL*100 + ci*12 + k]

    // precomputed staging tables
    int inOff[12];
    #pragma unroll
    for (int e = 0; e < 12; ++e) {
        int t = tid + e * 256;
        int off = -1;
        if (t < 2880) {
            int ci = t / 360, rem = t - ci * 360;
            int iy = rem / 20, ix = rem - iy * 20;
            int gy = tileY + iy - 1, gx = tileX + ix - 1;
            if (ix < 18 && (unsigned)gy < (unsigned)H && (unsigned)gx < (unsigned)W)
                off = ci * chStride + gy * W + gx;
        }
        inOff[e] = off;
    }
    unsigned wPack[18];   // (gOff<<13) | ldsOff ; bit31 = invalid(co>=C_out)
    #pragma unroll
    for (int e = 0; e < 18; ++e) {
        int t = tid + e * 256;                 // t < 4608
        int coL = t / 72, rem = t - coL * 72;
        int ciL = rem / 9, kk = rem - ciL * 9;
        unsigned lds = (unsigned)(coL * 100 + ciL * 12 + kk);
        unsigned g   = (unsigned)(coL * 2304 + ciL * 9 + kk);
        wPack[e] = (coBase + coL < C_out) ? ((g << 13) | lds) : (0x80000000u | lds);
    }

    float rIn[12], rW[18];
    auto loadIn = [&](int cc) {
        const float* isrc = srcBase + cc * chStride;
        #pragma unroll
        for (int e = 0; e < 12; ++e)
            rIn[e] = (inOff[e] >= 0) ? isrc[inOff[e]] : 0.f;
    };
    auto loadW = [&](int cc) {
        const float* wsrc = wBase + cc * 9;
        #pragma unroll
        for (int e = 0; e < 18; ++e) {
            unsigned p = wPack[e];
            rW[e] = (p & 0x80000000u) ? 0.f : wsrc[p >> 13];
        }
    };

    float acc[4][16] = {};
    loadIn(0); loadW(0);

    for (int cc = 0; cc < 256; cc += 8) {
        #pragma unroll
        for (int e = 0; e < 12; ++e) {
            int t = tid + e * 256;
            if (t < 2880) sIn[t] = rIn[e];
        }
        #pragma unroll
        for (int e = 0; e < 18; ++e)
            sW[wPack[e] & 8191u] = rW[e];
        __syncthreads();
        if (cc + 8 < 256) { loadIn(cc + 8); loadW(cc + 8); }

        #pragma unroll
        for (int ci = 0; ci < 8; ++ci) {
            float xr[6][6];
            #pragma unroll
            for (int iy = 0; iy < 6; ++iy) {
                const float4 a = *reinterpret_cast<const float4*>(&sIn[ci * 360 + (py0 + iy) * 20 + px0]);
                const float2 b = *reinterpret_cast<const float2*>(&sIn[ci * 360 + (py0 + iy) * 20 + px0 + 4]);
                xr[iy][0] = a.x; xr[iy][1] = a.y; xr[iy][2] = a.z; xr[iy][3] = a.w;
                xr[iy][4] = b.x; xr[iy][5] = b.y;
            }
            #pragma unroll
            for (int r = 0; r < 4; ++r) {
                const int wb = (cog4 + r) * 100 + ci * 12;
                const float4 w0 = *reinterpret_cast<const float4*>(&sW[wb]);
                const float4 w1 = *reinterpret_cast<const float4*>(&sW[wb + 4]);
                const float  w8 = sW[wb + 8];
                float wr[9];
                wr[0] = w0.x; wr[1] = w0.y; wr[2] = w0.z; wr[3] = w0.w;
                wr[4] = w1.x; wr[5] = w1.y; wr[6] = w1.z; wr[7] = w1.w; wr[8] = w8;
                #pragma unroll
                for (int oy = 0; oy < 4; ++oy)
                    #pragma unroll
                    for (int ox = 0; ox < 4; ++ox) {
                        float s = acc[r][oy * 4 + ox];
                        #pragma unroll
                        for (int ky = 0; ky < 3; ++ky)
                            #pragma unroll
                            for (int kx = 0; kx < 3; ++kx)
                                s = fmaf(xr[oy + ky][ox + kx], wr[ky * 3 + kx], s);
                        acc[r][oy * 4 + ox] = s;
                    }
            }
        }
        __syncthreads();
    }

    if (px0 >= W) return;   // lvl3 right-half threads
    #pragma unroll
    for (int r = 0; r < 4; ++r) {
        int coG = coBase + cog4 + r;
        if (coG >= C_out) continue;
        float b = bsel[coG];
        for (int oy = 0; oy < 4; ++oy) {
            int y = tileY + py0 + oy;
            if (y >= H) continue;   // lvl3 bottom rows
            float v0 = acc[r][oy * 4 + 0] + b;
            float v1 = acc[r][oy * 4 + 1] + b;
            float v2 = acc[r][oy * 4 + 2] + b;
            float v3 = acc[r][oy * 4 + 3] + b;
            if (epi == 0) {
                v0 = fmaxf(v0, 0.f); v1 = fmaxf(v1, 0.f); v2 = fmaxf(v2, 0.f); v3 = fmaxf(v3, 0.f);
                float* o = bufOut + ((size_t)(head * 4 + img) * 256 + coG) * CONCAT_PX
                                  + c_lvlPx[lvl] + y * W + tileX + px0;
                *reinterpret_cast<float4*>(o) = make_float4(v0, v1, v2, v3);
            } else if (epi == 1) {
                float s0 = 1.0f / (1.0f + expf(-v0));
                float s1 = 1.0f / (1.0f + expf(-v1));
                float s2 = 1.0f / (1.0f + expf(-v2));
                float s3 = 1.0f / (1.0f + expf(-v3));
                unsigned k0 = (s0 > 0.05f) ? __float_as_uint(s0) : 0u;
                unsigned k1 = (s1 > 0.05f) ? __float_as_uint(s1) : 0u;
                unsigned k2 = (s2 > 0.05f) ? __float_as_uint(s2) : 0u;
                unsigned k3 = (s3 > 0.05f) ? __float_as_uint(s3) : 0u;
                unsigned* o = keys + (size_t)img * IMG_KEY + c_keyOff[lvl]
                                   + (size_t)coG * HW + y * W + tileX + px0;
                *reinterpret_cast<uint4*>(o) = make_uint4(k0, k1, k2, k3);
            } else {
                int a = coG >> 2, jj = coG & 3;
                int pBase = y * W + tileX + px0;
                #pragma unroll
                for (int px = 0; px < 4; ++px) {
                    float v = acc[r][oy * 4 + px] + b;
                    regb[(size_t)img * IMG_REG + c_regOff[lvl] + (size_t)((pBase + px) * A_NUM + a) * 4 + jj] = v;
                }
            }
        }
    }
}

// ---------------------------------------------------------------------------
__global__ __launch_bounds__(256) void hist_k(const unsigned* __restrict__ keys,
                                              unsigned* __restrict__ hist)
{
    int il = blockIdx.y, img = il >> 2, lvl = il & 3;
    int n = c_keyCnt[lvl];
    int chunk = blockIdx.x * 16384;
    if (chunk >= n) return;
    __shared__ unsigned h[HBINS];   // 64 KB
    for (int t = threadIdx.x; t < HBINS; t += 256) h[t] = 0;
    __syncthreads();
    const uint4* k4 = (const uint4*)(keys + (size_t)img * IMG_KEY + c_keyOff[lvl]);
    int i0 = chunk >> 2, i1 = min(chunk + 16384, n) >> 2;
    for (int i = i0 + (int)threadIdx.x; i < i1; i += 256) {
        uint4 kv = k4[i];
        if (kv.x) atomicAdd(&h[kv.x >> 18], 1u);
        if (kv.y) atomicAdd(&h[kv.y >> 18], 1u);
        if (kv.z) atomicAdd(&h[kv.z >> 18], 1u);
        if (kv.w) atomicAdd(&h[kv.w >> 18], 1u);
    }
    __syncthreads();
    unsigned* gh = hist + (size_t)il * HBINS;
    for (int t = threadIdx.x; t < HBINS; t += 256)
        if (h[t]) atomicAdd(&gh[t], h[t]);
}

__global__ __launch_bounds__(256) void thresh_k(const unsigned* __restrict__ hist,
                                                unsigned* __restrict__ tbin)
{
    const unsigned* h = hist + (size_t)blockIdx.x * HBINS;
    __shared__ unsigned cs[256];
    int tid = threadIdx.x;
    unsigned s = 0;
    int base = tid * 64;
    for (int q = 0; q < 64; ++q) { int b = base + q; if (b >= 1) s += h[b]; }
    cs[tid] = s;
    __syncthreads();
    if (tid == 0) {
        unsigned total = 0, sel = 0;
        for (int c = 255; c >= 0; --c) {
            if (total + cs[c] >= 100u) {
                int lo = (c == 0) ? 1 : c * 64;
                for (int b = c * 64 + 63; b >= lo; --b) {
                    total += h[b];
                    if (total >= 100u) { sel = (unsigned)b; break; }
                }
                break;
            }
            total += cs[c];
        }
        tbin[blockIdx.x] = sel;
    }
}

// two-pass per-block aggregation: ONE global atomic per block
__global__ __launch_bounds__(256) void compact_k(const unsigned* __restrict__ keys,
                                                 const unsigned* __restrict__ tbin,
                                                 unsigned* __restrict__ cnt,
                                                 uint2* __restrict__ comp)
{
    int il = blockIdx.y, img = il >> 2, lvl = il & 3;
    int n = c_keyCnt[lvl];
    int chunk = blockIdx.x * 16384;
    if (chunk >= n) return;
    const unsigned* kbase = keys + (size_t)img * IMG_KEY + c_keyOff[lvl];
    const uint4* k4 = (const uint4*)kbase;
    unsigned thr = tbin[il] << 18;
    int shift = 12 - 2 * lvl;
    int hwm = (1 << shift) - 1;
    int i0 = chunk >> 2, i1 = min(chunk + 16384, n) >> 2;
    __shared__ unsigned lcnt, lbase, lcur;
    if (threadIdx.x == 0) { lcnt = 0; lcur = 0; }
    __syncthreads();
    unsigned myc = 0;
    for (int i = i0 + (int)threadIdx.x; i < i1; i += 256) {
        uint4 kv = k4[i];
        myc += (kv.x != 0u && kv.x >= thr);
        myc += (kv.y != 0u && kv.y >= thr);
        myc += (kv.z != 0u && kv.z >= thr);
        myc += (kv.w != 0u && kv.w >= thr);
    }
    if (myc) atomicAdd(&lcnt, myc);
    __syncthreads();
    if (threadIdx.x == 0 && lcnt) lbase = atomicAdd(&cnt[il], lcnt);
    __syncthreads();
    if (lcnt == 0) return;
    uint2* c = comp + (size_t)il * CAP;
    for (int i = i0 + (int)threadIdx.x; i < i1; i += 256) {
        uint4 kv = k4[i];
        unsigned kk[4] = {kv.x, kv.y, kv.z, kv.w};
        #pragma unroll
        for (int j = 0; j < 4; ++j) {
            unsigned key = kk[j];
            if (key != 0u && key >= thr) {
                int t = i * 4 + j;
                int co = t >> shift, p = t & hwm;
                int a = co / NCLS, cls = co - a * NCLS;
                unsigned idx = (unsigned)((p * A_NUM + a) * NCLS + cls);
                unsigned pos = lbase + atomicAdd(&lcur, 1u);
                if (pos < CAP) c[pos] = make_uint2(key, idx);
            }
        }
    }
}

// single-block bitonic sort of up to CAP candidates -> exact top-100
__global__ __launch_bounds__(256) void topsort_k(const unsigned* __restrict__ cnt,
                                                 const uint2* __restrict__ comp,
                                                 uint2* __restrict__ topk)
{
    __shared__ unsigned long long s[CAP];   // 64 KB
    int il = blockIdx.x, tid = threadIdx.x;
    int n = (int)min(cnt[il], (unsigned)CAP);
    const uint2* c = comp + (size_t)il * CAP;
    for (int i = tid; i < CAP; i += 256) {
        unsigned long long v = 0ull;
        if (i < n) {
            uint2 e = c[i];
            v = ((unsigned long long)e.x << 32) | (unsigned long long)(~e.y);
        }
        s[i] = v;
    }
    for (int k = 2; k <= CAP; k <<= 1) {
        for (int j = k >> 1; j > 0; j >>= 1) {
            __syncthreads();
            for (int p = tid; p < CAP / 2; p += 256) {
                int i = ((p & ~(j - 1)) << 1) | (p & (j - 1));
                int ixj = i | j;
                unsigned long long a = s[i], b = s[ixj];
                if (((i & k) == 0) ? (a < b) : (a > b)) { s[i] = b; s[ixj] = a; }
            }
        }
    }
    __syncthreads();
    if (tid < 100) {
        unsigned long long v = s[tid];
        topk[il * 100 + tid] = make_uint2((unsigned)(v >> 32), ~(unsigned)(v & 0xFFFFFFFFull));
    }
}

// ---------------------------------------------------------------------------
__global__ void decode_k(const uint2* __restrict__ topk, const float* __restrict__ regb,
                         float* __restrict__ cboxes, float* __restrict__ cscores,
                         int* __restrict__ clabels, const int* __restrict__ ph, const int* __restrict__ pw)
{
    int il = blockIdx.x, img = il >> 2, lvl = il & 3;
    int j = threadIdx.x;
    if (j >= 100) return;
    float imgW = (float)pw[0], imgH = (float)ph[0];
    uint2 tk = topk[il * 100 + j];
    int outP = img * 400 + lvl * 100 + j;
    if (tk.x == 0u) {
        cboxes[outP * 4 + 0] = 0.f; cboxes[outP * 4 + 1] = 0.f;
        cboxes[outP * 4 + 2] = 0.f; cboxes[outP * 4 + 3] = 0.f;
        cscores[outP] = -1.0f; clabels[outP] = -1;
        return;
    }
    float score = __uint_as_float(tk.x);
    unsigned idx = tk.y;
    int aidx = (int)(idx / NCLS);
    int lbl  = (int)(idx - (unsigned)aidx * NCLS);
    int a = aidx % A_NUM, p = aidx / A_NUM;
    int W = c_W[lvl];
    int y = p / W, x = p - y * W;
    int r = a / 3, si = a - r * 3;
    float ratio = (r == 0) ? 0.5f : ((r == 1) ? 1.0f : 2.0f);
    float size = c_sizes[lvl][si];
    float hr = sqrtf(ratio);
    float wr = 1.0f / hr;
    float wsz = wr * size, hsz = hr * size;
    float bw = rintf(wsz * 0.5f), bh = rintf(hsz * 0.5f);
    float sx = (float)(x * c_stride[lvl]), sy = (float)(y * c_stride[lvl]);
    float ax1 = fminf(fmaxf(sx - bw, 0.f), imgW);
    float ay1 = fminf(fmaxf(sy - bh, 0.f), imgH);
    float ax2 = fminf(fmaxf(sx + bw, 0.f), imgW);
    float ay2 = fminf(fmaxf(sy + bh, 0.f), imgH);
    float aw = ax2 - ax1, ah = ay2 - ay1;
    float cx = ax1 + 0.5f * aw, cy = ay1 + 0.5f * ah;
    const float* rel = regb + (size_t)img * IMG_REG + c_regOff[lvl] + (size_t)aidx * 4;
    float dx = rel[0], dy = rel[1];
    float dw = fminf(rel[2], 4.135166556742356f);
    float dh = fminf(rel[3], 4.135166556742356f);
    float pcx = dx * aw + cx, pcy = dy * ah + cy;
    float pwd = expf(dw) * aw, phd = expf(dh) * ah;
    float x1 = pcx - 0.5f * pwd, y1 = pcy - 0.5f * phd;
    float x2 = pcx + 0.5f * pwd, y2 = pcy + 0.5f * phd;
    cboxes[outP * 4 + 0] = fminf(fmaxf(x1, 0.f), imgW);
    cboxes[outP * 4 + 1] = fminf(fmaxf(y1, 0.f), imgH);
    cboxes[outP * 4 + 2] = fminf(fmaxf(x2, 0.f), imgW);
    cboxes[outP * 4 + 3] = fminf(fmaxf(y2, 0.f), imgH);
    cscores[outP] = score;
    clabels[outP] = lbl;
}

__global__ __launch_bounds__(512) void nms_k(const float* __restrict__ cboxes,
                                             const float* __restrict__ cscores,
                                             const int* __restrict__ clabels,
                                             const int* __restrict__ ph, const int* __restrict__ pw,
                                             float* __restrict__ out)
{
    int img = blockIdx.x, tid = threadIdx.x;
    __shared__ float sSc[512];
    __shared__ int   sPos[512];
    __shared__ float bx1[400], by1[400], bx2[400], by2[400], sAr[400];
    __shared__ int   sKeep[400], sLbl[400];
    float imgH = (float)ph[0], imgW = (float)pw[0];
    float offm = fmaxf(imgH, imgW) + 1.0f;

    sSc[tid] = (tid < 400) ? cscores[img * 400 + tid] : -3.0f;
    sPos[tid] = tid;
    __syncthreads();

    for (int k = 2; k <= 512; k <<= 1) {
        for (int jj = k >> 1; jj > 0; jj >>= 1) {
            int ixj = tid ^ jj;
            if (ixj > tid) {
                float s1 = sSc[tid], s2 = sSc[ixj];
                int p1 = sPos[tid], p2 = sPos[ixj];
                bool bef = (s1 > s2) || (s1 == s2 && p1 < p2);
                bool sw = ((tid & k) == 0) ? (!bef) : bef;
                if (sw) { sSc[tid] = s2; sSc[ixj] = s1; sPos[tid] = p2; sPos[ixj] = p1; }
            }
            __syncthreads();
        }
    }

    if (tid < 400) {
        int p = sPos[tid];
        int lbl = clabels[img * 400 + p];
        float ofs = (float)lbl * offm;
        float x1 = cboxes[(img * 400 + p) * 4 + 0] + ofs;
        float y1 = cboxes[(img * 400 + p) * 4 + 1] + ofs;
        float x2 = cboxes[(img * 400 + p) * 4 + 2] + ofs;
        float y2 = cboxes[(img * 400 + p) * 4 + 3] + ofs;
        bx1[tid] = x1; by1[tid] = y1; bx2[tid] = x2; by2[tid] = y2;
        sAr[tid] = (x2 - x1) * (y2 - y1);
        sLbl[tid] = lbl;
        sKeep[tid] = (sSc[tid] > 0.05f) ? 1 : 0;
    }
    __syncthreads();

    for (int i = 0; i < 400; ++i) {
        if (sKeep[i]) {
            for (int j2 = i + 1 + tid; j2 < 400; j2 += 512) {
                float ltx = fmaxf(bx1[i], bx1[j2]), lty = fmaxf(by1[i], by1[j2]);
                float rbx = fminf(bx2[i], bx2[j2]), rby = fminf(by2[i], by2[j2]);
                float ww = fmaxf(rbx - ltx, 0.f), hh = fmaxf(rby - lty, 0.f);
                float inter = ww * hh;
                float iou = inter / (((sAr[i] + sAr[j2]) - inter) + 1e-9f);
                if (iou > 0.5f) sKeep[j2] = 0;
            }
        }
        __syncthreads();
    }

    if (tid == 0) {
        int rank = 0;
        for (int i = 0; i < 400 && rank < 100; ++i) {
            if (sKeep[i]) {
                int p = sPos[i];
                for (int kk = 0; kk < 4; ++kk)
                    out[(img * 100 + rank) * 4 + kk] = cboxes[(img * 400 + p) * 4 + kk];
                out[1600 + img * 100 + rank] = sSc[i];
                out[2000 + img * 100 + rank] = (float)sLbl[i];
                ++rank;
            }
        }
        for (; rank < 100; ++rank) {
            for (int kk = 0; kk < 4; ++kk) out[(img * 100 + rank) * 4 + kk] = 0.f;
            out[1600 + img * 100 + rank] = 0.f;
            out[2000 + img * 100 + rank] = -1.0f;
        }
    }
}

// ---------------------------------------------------------------------------
extern "C" void kernel_launch(void* const* d_in, const int* in_sizes, int n_in,
                              void* d_out, int out_size, void* d_ws, size_t ws_size,
                              hipStream_t stream)
{
    const float* f0 = (const float*)d_in[0];
    const float* f1 = (const float*)d_in[1];
    const float* f2 = (const float*)d_in[2];
    const float* f3 = (const float*)d_in[3];
    const float* cls_tw = (const float*)d_in[4];
    const float* cls_tb = (const float*)d_in[5];
    const float* cls_ow = (const float*)d_in[6];
    const float* cls_ob = (const float*)d_in[7];
    const float* reg_tw = (const float*)d_in[8];
    const float* reg_tb = (const float*)d_in[9];
    const float* reg_ow = (const float*)d_in[10];
    const float* reg_ob = (const float*)d_in[11];
    const int* ph = (const int*)d_in[12];
    const int* pw = (const int*)d_in[13];
    float* out = (float*)d_out;

    char* ws = (char*)d_ws;
    size_t off = 0;
    auto alloc = [&](size_t bytes) -> void* {
        void* p = ws + off;
        off = (off + bytes + 255) & ~(size_t)255;
        return p;
    };
    // bufA aliased with keys (tower ping slab fits inside keys; keys written
    // only by the out-conv, after bufA's last read).
    float*    bufA   = (float*)alloc((size_t)4 * IMG_KEY * 4);                 // 62.7 MB
    unsigned* keys   = (unsigned*)bufA;
    float*    bufB   = (float*)alloc((size_t)2 * 4 * 256 * CONCAT_PX * 4);     // 44.6 MB
    float*    regb   = (float*)alloc((size_t)4 * IMG_REG * 4);
    unsigned* hist   = (unsigned*)alloc((size_t)16 * HBINS * 4);               // 1 MB
    unsigned* cnt    = (unsigned*)alloc(16 * 4);
    unsigned* tbin   = (unsigned*)alloc(16 * 4);
    uint2*    comp   = (uint2*)alloc((size_t)16 * CAP * 8);                    // 1 MB
    uint2*    topk   = (uint2*)alloc((size_t)1600 * 8);
    float*    cboxes = (float*)alloc((size_t)4 * 400 * 4 * 4);
    float*    cscores= (float*)alloc((size_t)4 * 400 * 4);
    int*      clabels= (int*)alloc((size_t)4 * 400 * 4);

    hipMemsetAsync(hist, 0, (size_t)16 * HBINS * 4, stream);
    hipMemsetAsync(cnt, 0, 64, stream);

    const size_t LW = (size_t)256 * 256 * 9;
    // tower: L0 f->A, L1 A->B, L2 B->A, L3 A->B
    float* seqIn[4]  = {nullptr, bufA, bufB, bufA};
    float* seqOut[4] = {bufA, bufB, bufA, bufB};
    for (int layer = 0; layer < 4; ++layer) {
        conv_fused<<<dim3(22, 4, 8), 256, 0, stream>>>(
            f0, f1, f2, f3, seqIn[layer], seqOut[layer],
            cls_tw + LW * layer, cls_tb + 256 * layer,
            reg_tw + LW * layer, reg_tb + 256 * layer,
            nullptr, nullptr, layer, 0);
    }
    // fused out-convs: reads bufB, writes keys(=bufA) + regb
    conv_fused<<<dim3(22, 13, 4), 256, 0, stream>>>(
        f0, f1, f2, f3, bufB, nullptr,
        cls_ow, cls_ob, reg_ow, reg_ob,
        keys, regb, 4, 1);

    hist_k<<<dim3(180, 16), 256, 0, stream>>>(keys, hist);
    thresh_k<<<16, 256, 0, stream>>>(hist, tbin);
    compact_k<<<dim3(180, 16), 256, 0, stream>>>(keys, tbin, cnt, comp);
    topsort_k<<<16, 256, 0, stream>>>(cnt, comp, topk);
    decode_k<<<16, 128, 0, stream>>>(topk, regb, cboxes, cscores, clabels, ph, pw);
    nms_k<<<4, 512, 0, stream>>>(cboxes, cscores, clabels, ph, pw, out);
}

// Round 6
// 4082.902 us; speedup vs baseline: 1.8352x; 1.4724x over previous
//
#include <hip/hip_runtime.h>
#include <math.h>

#define A_NUM 9
#define NCLS 80
#define IMG_KEY 3916800   // 720*5440
#define IMG_REG 195840    // 36*5440
#define CAP 8192
#define HBINS 16384
#define PCH 6192          // padded concat px per channel (halo +1 all sides)

__constant__ int   c_W[4]       = {64, 32, 16, 8};
__constant__ int   c_stride[4]  = {8, 16, 32, 64};
__constant__ float c_sizes[4][3]= {{32.f,40.f,50.f},{64.f,80.f,101.f},{128.f,161.f,203.f},{256.f,322.f,406.f}};
__constant__ int   c_keyOff[4]  = {0, 2949120, 3686400, 3870720};
__constant__ int   c_keyCnt[4]  = {2949120, 737280, 184320, 46080};
__constant__ int   c_regOff[4]  = {0, 147456, 184320, 193536};
__constant__ int   c_padW[4]    = {68, 36, 20, 12};
__constant__ int   c_padOff[4]  = {0, 4488, 5712, 6072};

// global_load_lds, 16B/lane: LDS dest = wave-uniform base + lane*16.
__device__ __forceinline__ void gl_lds16(const void* g, void* l) {
    __builtin_amdgcn_global_load_lds(
        (const __attribute__((address_space(1))) void*)g,
        (__attribute__((address_space(3))) void*)l, 16, 0, 0);
}

// ---------------------------------------------------------------------------
// prep: pad f0..f3 into Pin[img][ch][PCH] with zero halo
// ---------------------------------------------------------------------------
__global__ __launch_bounds__(256) void pad_in_k(
    const float* __restrict__ f0, const float* __restrict__ f1,
    const float* __restrict__ f2, const float* __restrict__ f3,
    float* __restrict__ Pin)
{
    int idx = blockIdx.x * 256 + threadIdx.x;
    const int total = 4 * 256 * PCH;
    if (idx >= total) return;
    int img = idx / (256 * PCH);
    int r = idx - img * (256 * PCH);
    int ch = r / PCH;
    int ppx = r - ch * PCH;
    int lvl = (ppx < 4488) ? 0 : (ppx < 5712 ? 1 : (ppx < 6072 ? 2 : 3));
    int off = c_padOff[lvl], pw = c_padW[lvl], H = 64 >> lvl;
    int rr = (ppx - off) / pw;
    int cc = (ppx - off) - rr * pw;
    float v = 0.f;
    if (rr >= 1 && rr <= H && cc >= 1 && cc <= H) {
        const float* f = (lvl == 0) ? f0 : ((lvl == 1) ? f1 : ((lvl == 2) ? f2 : f3));
        v = f[((size_t)img * 256 + ch) * H * H + (rr - 1) * H + (cc - 1)];
    }
    Pin[idx] = v;
}

// ---------------------------------------------------------------------------
// prep: repack conv weights [L][C_out][256][9] -> [L][cg][chunk32][6400]
// LDS image: e -> coL=e/100, ciL=(e%100)/12, k=(e%100)%12 ; zero pads.
// ---------------------------------------------------------------------------
__global__ __launch_bounds__(256) void repack_k(
    const float* __restrict__ src, float* __restrict__ dst,
    int C_out, int nLayers, int nCg, int total)
{
    int idx = blockIdx.x * 256 + threadIdx.x;
    if (idx >= total) return;
    int per_layer = nCg * 204800;
    int layer = idx / per_layer;
    int r = idx - layer * per_layer;
    int cg = r / 204800;
    int r2 = r - cg * 204800;
    int chunk = r2 / 6400;
    int e = r2 - chunk * 6400;
    int coL = e / 100, rem = e - coL * 100;
    int ciL = rem / 12, k = rem - ciL * 12;
    int co = cg * 64 + coL;
    float v = 0.f;
    if (k < 9 && ciL < 8 && co < C_out)
        v = src[((size_t)(layer * C_out + co)) * 2304 + (chunk * 8 + ciL) * 9 + k];
    dst[idx] = v;
}

// ---------------------------------------------------------------------------
// Fused 3x3 SAME conv, fp32, 8x16-px tile x 64 co per block (43 tiles/level-set).
// Thread tile 4co x (2x4)px. Staging = global_load_lds width-16 only:
//  - sIn: 1600 floats from pre-padded activations (no bounds checks)
//  - sW : 6400 floats flat copy of pre-repacked weight chunk
// ~9 staging instrs/wave/chunk vs ~120 VALU+DS before (R3). FMA order identical.
// ---------------------------------------------------------------------------
__global__ __launch_bounds__(256, 3) void conv_fused(
    const float* __restrict__ Pin, const float* __restrict__ bufIn,
    float* __restrict__ bufOut,
    const float* __restrict__ repA, const float* __restrict__ bA,
    const float* __restrict__ repB, const float* __restrict__ bB,
    unsigned* __restrict__ keys, float* __restrict__ regb,
    int mode, int usePin)
{
    const int tid = threadIdx.x;
    const int lane = tid & 63;
    const int wv = tid >> 6;
    const int t43 = blockIdx.x;

    int img, head, coBase, C_out, epi;
    if (mode == 0) {
        img = blockIdx.z & 3; head = blockIdx.z >> 2;
        coBase = blockIdx.y * 64; C_out = 256; epi = 0;
    } else {
        img = blockIdx.z;
        if (blockIdx.y < 12) { head = 0; coBase = blockIdx.y * 64; C_out = 720; epi = 1; }
        else                 { head = 1; coBase = 0;               C_out = 36;  epi = 2; }
    }
    const float* bsel = head ? bB : bA;
    const float* wsel = head ? repB : repA;
    const float* wChunkBase = wsel + (size_t)(coBase >> 6) * 204800;

    int lvl, ty, tx;
    if (t43 < 32)      { lvl = 0; ty = t43 >> 2; tx = t43 & 3; }
    else if (t43 < 40) { int u = t43 - 32; lvl = 1; ty = u >> 1; tx = u & 1; }
    else if (t43 < 42) { lvl = 2; ty = t43 - 40; tx = 0; }
    else               { lvl = 3; ty = 0; tx = 0; }
    const int W = 64 >> lvl, HW = W * W;
    const int pW = c_padW[lvl];
    const int tileY = ty * 8, tileX = tx * 16;

    const float* srcBase = usePin
        ? Pin   + ((size_t)img * 256) * PCH + c_padOff[lvl]
        : bufIn + ((size_t)(head * 4 + img) * 256) * PCH + c_padOff[lvl];

    const int cog4 = (tid >> 4) * 4;
    const int pg   = tid & 15;
    const int py0  = (pg >> 2) * 2;
    const int px0  = (pg & 3) * 4;

    __shared__ float sIn[1600];   // 8ci x 10 rows x 20 cols (padded-space)
    __shared__ float sW[6400];    // flat repacked chunk [coL*100 + ci*12 + k]

    // per-lane input staging table (2 instr slots per wave: jj = wv, wv+4)
    int inByte[2]; bool inOk[2];
    #pragma unroll
    for (int p = 0; p < 2; ++p) {
        int jj = wv + 4 * p;
        bool ok = (jj < 6) || (jj == 6 && lane < 16);
        int f = jj * 256 + lane * 4;
        if (f > 1596) f = 1596;
        int ci = f / 200, rem = f - ci * 200;
        int iy = rem / 20, c4 = rem - iy * 20;
        inByte[p] = 4 * (ci * PCH + (tileY + iy) * pW + tileX + c4);
        inOk[p] = ok;
    }

    float acc[4][8] = {};
    const char* srcBytes = (const char*)srcBase;
    const char* wBytes = (const char*)wChunkBase;

    #pragma unroll 1
    for (int ck = 0; ck < 32; ++ck) {
        // ---- stage via async global->LDS (prev compute done: trailing barrier)
        const char* sA = srcBytes + (size_t)ck * (8 * PCH * 4);
        #pragma unroll
        for (int p = 0; p < 2; ++p)
            if (inOk[p]) gl_lds16(sA + inByte[p], (char*)sIn + (wv + 4 * p) * 1024);
        const char* wA_ = wBytes + (size_t)ck * 25600;
        for (int jj = wv; jj < 25; jj += 4)
            gl_lds16(wA_ + jj * 1024 + lane * 16, (char*)sW + jj * 1024);
        __syncthreads();   // drains vmcnt -> LDS ready

        #pragma unroll
        for (int ci = 0; ci < 8; ++ci) {
            float xr[4][6];
            #pragma unroll
            for (int iy = 0; iy < 4; ++iy) {
                const float4 a = *reinterpret_cast<const float4*>(&sIn[ci * 200 + (py0 + iy) * 20 + px0]);
                const float2 b = *reinterpret_cast<const float2*>(&sIn[ci * 200 + (py0 + iy) * 20 + px0 + 4]);
                xr[iy][0] = a.x; xr[iy][1] = a.y; xr[iy][2] = a.z; xr[iy][3] = a.w;
                xr[iy][4] = b.x; xr[iy][5] = b.y;
            }
            #pragma unroll
            for (int r = 0; r < 4; ++r) {
                const int wb = (cog4 + r) * 100 + ci * 12;
                const float4 w0 = *reinterpret_cast<const float4*>(&sW[wb]);
                const float4 w1 = *reinterpret_cast<const float4*>(&sW[wb + 4]);
                const float  w8 = sW[wb + 8];
                float wr[9];
                wr[0] = w0.x; wr[1] = w0.y; wr[2] = w0.z; wr[3] = w0.w;
                wr[4] = w1.x; wr[5] = w1.y; wr[6] = w1.z; wr[7] = w1.w; wr[8] = w8;
                #pragma unroll
                for (int py = 0; py < 2; ++py)
                    #pragma unroll
                    for (int px = 0; px < 4; ++px) {
                        float s = acc[r][py * 4 + px];
                        #pragma unroll
                        for (int ky = 0; ky < 3; ++ky)
                            #pragma unroll
                            for (int kx = 0; kx < 3; ++kx)
                                s = fmaf(xr[py + ky][px + kx], wr[ky * 3 + kx], s);
                        acc[r][py * 4 + px] = s;
                    }
            }
        }
        __syncthreads();   // all reads done before next chunk overwrites LDS
    }

    if (px0 >= W) return;   // lvl3 right-half threads
    #pragma unroll
    for (int r = 0; r < 4; ++r) {
        int coG = coBase + cog4 + r;
        if (coG >= C_out) continue;
        float b = bsel[coG];
        for (int py = 0; py < 2; ++py) {
            int y = tileY + py0 + py;
            float v0 = acc[r][py * 4 + 0] + b;
            float v1 = acc[r][py * 4 + 1] + b;
            float v2 = acc[r][py * 4 + 2] + b;
            float v3 = acc[r][py * 4 + 3] + b;
            if (epi == 0) {
                v0 = fmaxf(v0, 0.f); v1 = fmaxf(v1, 0.f); v2 = fmaxf(v2, 0.f); v3 = fmaxf(v3, 0.f);
                // padded layout, interior offset (+1,+1); scalar stores (unaligned +1)
                float* o = bufOut + ((size_t)(head * 4 + img) * 256 + coG) * PCH
                                  + c_padOff[lvl] + (y + 1) * pW + (tileX + px0 + 1);
                o[0] = v0; o[1] = v1; o[2] = v2; o[3] = v3;
            } else if (epi == 1) {
                float s0 = 1.0f / (1.0f + expf(-v0));
                float s1 = 1.0f / (1.0f + expf(-v1));
                float s2 = 1.0f / (1.0f + expf(-v2));
                float s3 = 1.0f / (1.0f + expf(-v3));
                unsigned k0 = (s0 > 0.05f) ? __float_as_uint(s0) : 0u;
                unsigned k1 = (s1 > 0.05f) ? __float_as_uint(s1) : 0u;
                unsigned k2 = (s2 > 0.05f) ? __float_as_uint(s2) : 0u;
                unsigned k3 = (s3 > 0.05f) ? __float_as_uint(s3) : 0u;
                unsigned* o = keys + (size_t)img * IMG_KEY + c_keyOff[lvl]
                                   + (size_t)coG * HW + y * W + tileX + px0;
                *reinterpret_cast<uint4*>(o) = make_uint4(k0, k1, k2, k3);
            } else {
                int a = coG >> 2, jj = coG & 3;
                int pBase = y * W + tileX + px0;
                #pragma unroll
                for (int px = 0; px < 4; ++px) {
                    float v = acc[r][py * 4 + px] + b;
                    regb[(size_t)img * IMG_REG + c_regOff[lvl] + (size_t)((pBase + px) * A_NUM + a) * 4 + jj] = v;
                }
            }
        }
    }
}

// ---------------------------------------------------------------------------
__global__ __launch_bounds__(256) void hist_k(const unsigned* __restrict__ keys,
                                              unsigned* __restrict__ hist)
{
    int il = blockIdx.y, img = il >> 2, lvl = il & 3;
    int n = c_keyCnt[lvl];
    int chunk = blockIdx.x * 16384;
    if (chunk >= n) return;
    __shared__ unsigned h[HBINS];
    for (int t = threadIdx.x; t < HBINS; t += 256) h[t] = 0;
    __syncthreads();
    const uint4* k4 = (const uint4*)(keys + (size_t)img * IMG_KEY + c_keyOff[lvl]);
    int i0 = chunk >> 2, i1 = min(chunk + 16384, n) >> 2;
    for (int i = i0 + (int)threadIdx.x; i < i1; i += 256) {
        uint4 kv = k4[i];
        if (kv.x) atomicAdd(&h[kv.x >> 18], 1u);
        if (kv.y) atomicAdd(&h[kv.y >> 18], 1u);
        if (kv.z) atomicAdd(&h[kv.z >> 18], 1u);
        if (kv.w) atomicAdd(&h[kv.w >> 18], 1u);
    }
    __syncthreads();
    unsigned* gh = hist + (size_t)il * HBINS;
    for (int t = threadIdx.x; t < HBINS; t += 256)
        if (h[t]) atomicAdd(&gh[t], h[t]);
}

__global__ __launch_bounds__(256) void thresh_k(const unsigned* __restrict__ hist,
                                                unsigned* __restrict__ tbin)
{
    const unsigned* h = hist + (size_t)blockIdx.x * HBINS;
    __shared__ unsigned cs[256];
    int tid = threadIdx.x;
    unsigned s = 0;
    int base = tid * 64;
    for (int q = 0; q < 64; ++q) { int b = base + q; if (b >= 1) s += h[b]; }
    cs[tid] = s;
    __syncthreads();
    if (tid == 0) {
        unsigned total = 0, sel = 0;
        for (int c = 255; c >= 0; --c) {
            if (total + cs[c] >= 100u) {
                int lo = (c == 0) ? 1 : c * 64;
                for (int b = c * 64 + 63; b >= lo; --b) {
                    total += h[b];
                    if (total >= 100u) { sel = (unsigned)b; break; }
                }
                break;
            }
            total += cs[c];
        }
        tbin[blockIdx.x] = sel;
    }
}

__global__ __launch_bounds__(256) void compact_k(const unsigned* __restrict__ keys,
                                                 const unsigned* __restrict__ tbin,
                                                 unsigned* __restrict__ cnt,
                                                 uint2* __restrict__ comp)
{
    int il = blockIdx.y, img = il >> 2, lvl = il & 3;
    int n = c_keyCnt[lvl];
    int chunk = blockIdx.x * 16384;
    if (chunk >= n) return;
    const uint4* k4 = (const uint4*)(keys + (size_t)img * IMG_KEY + c_keyOff[lvl]);
    unsigned thr = tbin[il] << 18;
    int shift = 12 - 2 * lvl;
    int hwm = (1 << shift) - 1;
    int i0 = chunk >> 2, i1 = min(chunk + 16384, n) >> 2;
    __shared__ unsigned lcnt, lbase, lcur;
    if (threadIdx.x == 0) { lcnt = 0; lcur = 0; }
    __syncthreads();
    unsigned myc = 0;
    for (int i = i0 + (int)threadIdx.x; i < i1; i += 256) {
        uint4 kv = k4[i];
        myc += (kv.x != 0u && kv.x >= thr);
        myc += (kv.y != 0u && kv.y >= thr);
        myc += (kv.z != 0u && kv.z >= thr);
        myc += (kv.w != 0u && kv.w >= thr);
    }
    if (myc) atomicAdd(&lcnt, myc);
    __syncthreads();
    if (threadIdx.x == 0 && lcnt) lbase = atomicAdd(&cnt[il], lcnt);
    __syncthreads();
    if (lcnt == 0) return;
    uint2* c = comp + (size_t)il * CAP;
    for (int i = i0 + (int)threadIdx.x; i < i1; i += 256) {
        uint4 kv = k4[i];
        unsigned kk[4] = {kv.x, kv.y, kv.z, kv.w};
        #pragma unroll
        for (int j = 0; j < 4; ++j) {
            unsigned key = kk[j];
            if (key != 0u && key >= thr) {
                int t = i * 4 + j;
                int co = t >> shift, p = t & hwm;
                int a = co / NCLS, cls = co - a * NCLS;
                unsigned idx = (unsigned)((p * A_NUM + a) * NCLS + cls);
                unsigned pos = lbase + atomicAdd(&lcur, 1u);
                if (pos < CAP) c[pos] = make_uint2(key, idx);
            }
        }
    }
}

__global__ __launch_bounds__(256) void topsort_k(const unsigned* __restrict__ cnt,
                                                 const uint2* __restrict__ comp,
                                                 uint2* __restrict__ topk)
{
    __shared__ unsigned long long s[CAP];
    int il = blockIdx.x, tid = threadIdx.x;
    int n = (int)min(cnt[il], (unsigned)CAP);
    const uint2* c = comp + (size_t)il * CAP;
    for (int i = tid; i < CAP; i += 256) {
        unsigned long long v = 0ull;
        if (i < n) {
            uint2 e = c[i];
            v = ((unsigned long long)e.x << 32) | (unsigned long long)(~e.y);
        }
        s[i] = v;
    }
    for (int k = 2; k <= CAP; k <<= 1) {
        for (int j = k >> 1; j > 0; j >>= 1) {
            __syncthreads();
            for (int p = tid; p < CAP / 2; p += 256) {
                int i = ((p & ~(j - 1)) << 1) | (p & (j - 1));
                int ixj = i | j;
                unsigned long long a = s[i], b = s[ixj];
                if (((i & k) == 0) ? (a < b) : (a > b)) { s[i] = b; s[ixj] = a; }
            }
        }
    }
    __syncthreads();
    if (tid < 100) {
        unsigned long long v = s[tid];
        topk[il * 100 + tid] = make_uint2((unsigned)(v >> 32), ~(unsigned)(v & 0xFFFFFFFFull));
    }
}

// ---------------------------------------------------------------------------
__global__ void decode_k(const uint2* __restrict__ topk, const float* __restrict__ regb,
                         float* __restrict__ cboxes, float* __restrict__ cscores,
                         int* __restrict__ clabels, const int* __restrict__ ph, const int* __restrict__ pw)
{
    int il = blockIdx.x, img = il >> 2, lvl = il & 3;
    int j = threadIdx.x;
    if (j >= 100) return;
    float imgW = (float)pw[0], imgH = (float)ph[0];
    uint2 tk = topk[il * 100 + j];
    int outP = img * 400 + lvl * 100 + j;
    if (tk.x == 0u) {
        cboxes[outP * 4 + 0] = 0.f; cboxes[outP * 4 + 1] = 0.f;
        cboxes[outP * 4 + 2] = 0.f; cboxes[outP * 4 + 3] = 0.f;
        cscores[outP] = -1.0f; clabels[outP] = -1;
        return;
    }
    float score = __uint_as_float(tk.x);
    unsigned idx = tk.y;
    int aidx = (int)(idx / NCLS);
    int lbl  = (int)(idx - (unsigned)aidx * NCLS);
    int a = aidx % A_NUM, p = aidx / A_NUM;
    int W = c_W[lvl];
    int y = p / W, x = p - y * W;
    int r = a / 3, si = a - r * 3;
    float ratio = (r == 0) ? 0.5f : ((r == 1) ? 1.0f : 2.0f);
    float size = c_sizes[lvl][si];
    float hr = sqrtf(ratio);
    float wr = 1.0f / hr;
    float wsz = wr * size, hsz = hr * size;
    float bw = rintf(wsz * 0.5f), bh = rintf(hsz * 0.5f);
    float sx = (float)(x * c_stride[lvl]), sy = (float)(y * c_stride[lvl]);
    float ax1 = fminf(fmaxf(sx - bw, 0.f), imgW);
    float ay1 = fminf(fmaxf(sy - bh, 0.f), imgH);
    float ax2 = fminf(fmaxf(sx + bw, 0.f), imgW);
    float ay2 = fminf(fmaxf(sy + bh, 0.f), imgH);
    float aw = ax2 - ax1, ah = ay2 - ay1;
    float cx = ax1 + 0.5f * aw, cy = ay1 + 0.5f * ah;
    const float* rel = regb + (size_t)img * IMG_REG + c_regOff[lvl] + (size_t)aidx * 4;
    float dx = rel[0], dy = rel[1];
    float dw = fminf(rel[2], 4.135166556742356f);
    float dh = fminf(rel[3], 4.135166556742356f);
    float pcx = dx * aw + cx, pcy = dy * ah + cy;
    float pwd = expf(dw) * aw, phd = expf(dh) * ah;
    float x1 = pcx - 0.5f * pwd, y1 = pcy - 0.5f * phd;
    float x2 = pcx + 0.5f * pwd, y2 = pcy + 0.5f * phd;
    cboxes[outP * 4 + 0] = fminf(fmaxf(x1, 0.f), imgW);
    cboxes[outP * 4 + 1] = fminf(fmaxf(y1, 0.f), imgH);
    cboxes[outP * 4 + 2] = fminf(fmaxf(x2, 0.f), imgW);
    cboxes[outP * 4 + 3] = fminf(fmaxf(y2, 0.f), imgH);
    cscores[outP] = score;
    clabels[outP] = lbl;
}

__global__ __launch_bounds__(512) void nms_k(const float* __restrict__ cboxes,
                                             const float* __restrict__ cscores,
                                             const int* __restrict__ clabels,
                                             const int* __restrict__ ph, const int* __restrict__ pw,
                                             float* __restrict__ out)
{
    int img = blockIdx.x, tid = threadIdx.x;
    __shared__ float sSc[512];
    __shared__ int   sPos[512];
    __shared__ float bx1[400], by1[400], bx2[400], by2[400], sAr[400];
    __shared__ int   sKeep[400], sLbl[400];
    float imgH = (float)ph[0], imgW = (float)pw[0];
    float offm = fmaxf(imgH, imgW) + 1.0f;

    sSc[tid] = (tid < 400) ? cscores[img * 400 + tid] : -3.0f;
    sPos[tid] = tid;
    __syncthreads();

    for (int k = 2; k <= 512; k <<= 1) {
        for (int jj = k >> 1; jj > 0; jj >>= 1) {
            int ixj = tid ^ jj;
            if (ixj > tid) {
                float s1 = sSc[tid], s2 = sSc[ixj];
                int p1 = sPos[tid], p2 = sPos[ixj];
                bool bef = (s1 > s2) || (s1 == s2 && p1 < p2);
                bool sw = ((tid & k) == 0) ? (!bef) : bef;
                if (sw) { sSc[tid] = s2; sSc[ixj] = s1; sPos[tid] = p2; sPos[ixj] = p1; }
            }
            __syncthreads();
        }
    }

    if (tid < 400) {
        int p = sPos[tid];
        int lbl = clabels[img * 400 + p];
        float ofs = (float)lbl * offm;
        float x1 = cboxes[(img * 400 + p) * 4 + 0] + ofs;
        float y1 = cboxes[(img * 400 + p) * 4 + 1] + ofs;
        float x2 = cboxes[(img * 400 + p) * 4 + 2] + ofs;
        float y2 = cboxes[(img * 400 + p) * 4 + 3] + ofs;
        bx1[tid] = x1; by1[tid] = y1; bx2[tid] = x2; by2[tid] = y2;
        sAr[tid] = (x2 - x1) * (y2 - y1);
        sLbl[tid] = lbl;
        sKeep[tid] = (sSc[tid] > 0.05f) ? 1 : 0;
    }
    __syncthreads();

    for (int i = 0; i < 400; ++i) {
        if (sKeep[i]) {
            for (int j2 = i + 1 + tid; j2 < 400; j2 += 512) {
                float ltx = fmaxf(bx1[i], bx1[j2]), lty = fmaxf(by1[i], by1[j2]);
                float rbx = fminf(bx2[i], bx2[j2]), rby = fminf(by2[i], by2[j2]);
                float ww = fmaxf(rbx - ltx, 0.f), hh = fmaxf(rby - lty, 0.f);
                float inter = ww * hh;
                float iou = inter / (((sAr[i] + sAr[j2]) - inter) + 1e-9f);
                if (iou > 0.5f) sKeep[j2] = 0;
            }
        }
        __syncthreads();
    }

    if (tid == 0) {
        int rank = 0;
        for (int i = 0; i < 400 && rank < 100; ++i) {
            if (sKeep[i]) {
                int p = sPos[i];
                for (int kk = 0; kk < 4; ++kk)
                    out[(img * 100 + rank) * 4 + kk] = cboxes[(img * 400 + p) * 4 + kk];
                out[1600 + img * 100 + rank] = sSc[i];
                out[2000 + img * 100 + rank] = (float)sLbl[i];
                ++rank;
            }
        }
        for (; rank < 100; ++rank) {
            for (int kk = 0; kk < 4; ++kk) out[(img * 100 + rank) * 4 + kk] = 0.f;
            out[1600 + img * 100 + rank] = 0.f;
            out[2000 + img * 100 + rank] = -1.0f;
        }
    }
}

// ---------------------------------------------------------------------------
extern "C" void kernel_launch(void* const* d_in, const int* in_sizes, int n_in,
                              void* d_out, int out_size, void* d_ws, size_t ws_size,
                              hipStream_t stream)
{
    const float* f0 = (const float*)d_in[0];
    const float* f1 = (const float*)d_in[1];
    const float* f2 = (const float*)d_in[2];
    const float* f3 = (const float*)d_in[3];
    const float* cls_tw = (const float*)d_in[4];
    const float* cls_tb = (const float*)d_in[5];
    const float* cls_ow = (const float*)d_in[6];
    const float* cls_ob = (const float*)d_in[7];
    const float* reg_tw = (const float*)d_in[8];
    const float* reg_tb = (const float*)d_in[9];
    const float* reg_ow = (const float*)d_in[10];
    const float* reg_ob = (const float*)d_in[11];
    const int* ph = (const int*)d_in[12];
    const int* pw = (const int*)d_in[13];
    float* out = (float*)d_out;

    char* ws = (char*)d_ws;
    size_t off = 0;
    auto alloc = [&](size_t bytes) -> void* {
        void* p = ws + off;
        off = (off + bytes + 1023) & ~(size_t)1023;
        return p;
    };
    const size_t ACT = (size_t)2 * 4 * 256 * PCH * 4;         // 50.7 MB padded acts
    const size_t KEYS = (size_t)4 * IMG_KEY * 4;              // 62.7 MB
    float*    Pin    = (float*)alloc((size_t)4 * 256 * PCH * 4 + 4096);
    float*    slabA  = (float*)alloc((KEYS > ACT ? KEYS : ACT) + 4096);
    unsigned* keys   = (unsigned*)slabA;
    float*    bufA   = slabA;
    float*    bufB   = (float*)alloc(ACT + 4096);
    float*    repCT  = (float*)alloc((size_t)4 * 4 * 204800 * 4);   // tower cls
    float*    repRT  = (float*)alloc((size_t)4 * 4 * 204800 * 4);   // tower reg
    float*    repCO  = (float*)alloc((size_t)12 * 204800 * 4);      // cls out
    float*    repRO  = (float*)alloc((size_t)1 * 204800 * 4);       // reg out
    float*    regb   = (float*)alloc((size_t)4 * IMG_REG * 4);
    unsigned* hist   = (unsigned*)alloc((size_t)16 * HBINS * 4);
    unsigned* cnt    = (unsigned*)alloc(16 * 4);
    unsigned* tbin   = (unsigned*)alloc(16 * 4);
    uint2*    comp   = (uint2*)alloc((size_t)16 * CAP * 8);
    uint2*    topk   = (uint2*)alloc((size_t)1600 * 8);
    float*    cboxes = (float*)alloc((size_t)4 * 400 * 4 * 4);
    float*    cscores= (float*)alloc((size_t)4 * 400 * 4);
    int*      clabels= (int*)alloc((size_t)4 * 400 * 4);

    // zero halos (full act slabs) + accumulators
    hipMemsetAsync(bufA, 0, ACT, stream);
    hipMemsetAsync(bufB, 0, ACT, stream);
    hipMemsetAsync(hist, 0, (size_t)16 * HBINS * 4, stream);
    hipMemsetAsync(cnt, 0, 64, stream);

    // prep: pad inputs, repack weights
    {
        int tot = 4 * 256 * PCH;
        pad_in_k<<<(tot + 255) / 256, 256, 0, stream>>>(f0, f1, f2, f3, Pin);
        int tCT = 4 * 4 * 204800;
        repack_k<<<(tCT + 255) / 256, 256, 0, stream>>>(cls_tw, repCT, 256, 4, 4, tCT);
        repack_k<<<(tCT + 255) / 256, 256, 0, stream>>>(reg_tw, repRT, 256, 4, 4, tCT);
        int tCO = 12 * 204800;
        repack_k<<<(tCO + 255) / 256, 256, 0, stream>>>(cls_ow, repCO, 720, 1, 12, tCO);
        int tRO = 204800;
        repack_k<<<(tRO + 255) / 256, 256, 0, stream>>>(reg_ow, repRO, 36, 1, 1, tRO);
    }

    // tower: L0 Pin->A, L1 A->B, L2 B->A, L3 A->B   (per-layer repack offset 819200 floats)
    conv_fused<<<dim3(43, 4, 8), 256, 0, stream>>>(Pin, Pin, bufA,
        repCT, cls_tb, repRT, reg_tb, keys, regb, 0, 1);
    conv_fused<<<dim3(43, 4, 8), 256, 0, stream>>>(Pin, bufA, bufB,
        repCT + 819200, cls_tb + 256, repRT + 819200, reg_tb + 256, keys, regb, 0, 0);
    conv_fused<<<dim3(43, 4, 8), 256, 0, stream>>>(Pin, bufB, bufA,
        repCT + 2 * 819200, cls_tb + 512, repRT + 2 * 819200, reg_tb + 512, keys, regb, 0, 0);
    conv_fused<<<dim3(43, 4, 8), 256, 0, stream>>>(Pin, bufA, bufB,
        repCT + 3 * 819200, cls_tb + 768, repRT + 3 * 819200, reg_tb + 768, keys, regb, 0, 0);
    // out-convs: read B, write keys(=slabA, free now) + regb
    conv_fused<<<dim3(43, 13, 4), 256, 0, stream>>>(Pin, bufB, nullptr,
        repCO, cls_ob, repRO, reg_ob, keys, regb, 1, 0);

    hist_k<<<dim3(180, 16), 256, 0, stream>>>(keys, hist);
    thresh_k<<<16, 256, 0, stream>>>(hist, tbin);
    compact_k<<<dim3(180, 16), 256, 0, stream>>>(keys, tbin, cnt, comp);
    topsort_k<<<16, 256, 0, stream>>>(cnt, comp, topk);
    decode_k<<<16, 128, 0, stream>>>(topk, regb, cboxes, cscores, clabels, ph, pw);
    nms_k<<<4, 512, 0, stream>>>(cboxes, cscores, clabels, ph, pw, out);
}